// Round 3
// baseline (7925.538 us; speedup 1.0000x reference)
//
#include <hip/hip_runtime.h>

// ---------------------------------------------------------------------------
// LSTM encoder: B=64, S=512, E=256, H=512, gates 4H=2048 (order i,f,g,o)
// Strategy:
//   P  (prep): repack W_hh/W_ih to f16 in [k2][unit][gate][2] layout, bias sum,
//              zero h/c state.  (re-run every call: ws is re-poisoned)
//   Q  (xg):   x_gates = emb[tok] @ W_ih.T + b_ih + b_hh  -> f16, packed
//              [tau][unit][gate] so the recurrent kernel loads short4/lane.
//   R  (rec):  64 blocks (1/batch elem) x 1024 thr; h,c persist in LDS/regs;
//              2 barriers/step; W_hh streamed from L2 via v_dot2_f32_f16.
// Fallback (ws too small): naive all-f32 kernel straight from d_in.
//
// R2 bugfix: prep W-section bound was 262144 (k2 ran to 511, OOB read past
// W_hh end -> HSA memory fault; Wp writes overran into Wip/bsum/h/c).
// Correct count = 256 k2-pairs * 512 units = 131072.
// ---------------------------------------------------------------------------

typedef _Float16 half2_t __attribute__((ext_vector_type(2)));
typedef short short4_t __attribute__((ext_vector_type(4)));

__device__ __forceinline__ float dot2h(int w, int h, float c) {
#if __has_builtin(__builtin_amdgcn_fdot2)
  return __builtin_amdgcn_fdot2(__builtin_bit_cast(half2_t, w),
                                __builtin_bit_cast(half2_t, h), c, false);
#else
  half2_t a = __builtin_bit_cast(half2_t, w);
  half2_t b = __builtin_bit_cast(half2_t, h);
  return fmaf((float)a[1], (float)b[1], fmaf((float)a[0], (float)b[0], c));
#endif
}

__device__ __forceinline__ float sigm(float x) { return 1.0f / (1.0f + __expf(-x)); }
__device__ __forceinline__ float tanh_(float x) { return 1.0f - 2.0f / (__expf(2.0f * x) + 1.0f); }

// ---------------------------------------------------------------------------
// P: repack weights. Wp[(k2*512+j)*8 + g*2 + kk] = W_hh[g*512+j][2*k2+kk]
//    (k2<256).  Wip same with k2<128 from W_ih.  bsum[j*4+g]=b_ih+b_hh.
// Section layout (idx): [0,131072) W pack | [131072,133120) bsum |
//                       [133120,165888) hstate | [165888,198656) cstate
// ---------------------------------------------------------------------------
__global__ __launch_bounds__(256) void prep_kernel(
    const float* __restrict__ W_hh, const float* __restrict__ W_ih,
    const float* __restrict__ b_ih, const float* __restrict__ b_hh,
    _Float16* __restrict__ Wp, _Float16* __restrict__ Wip,
    float* __restrict__ bsum, _Float16* __restrict__ hstate,
    float* __restrict__ cstate) {
  const int NW = 131072;  // 256 k2-pairs * 512 units
  const int total = NW + 2048 + 32768 + 32768;  // 198656
  for (int idx = blockIdx.x * blockDim.x + threadIdx.x; idx < total;
       idx += gridDim.x * blockDim.x) {
    if (idx < NW) {
      int j = idx & 511, k2 = idx >> 9;  // k2 in [0,256)
#pragma unroll
      for (int g = 0; g < 4; ++g) {
        Wp[(size_t)(k2 * 512 + j) * 8 + g * 2 + 0] =
            (_Float16)W_hh[(size_t)(g * 512 + j) * 512 + 2 * k2 + 0];
        Wp[(size_t)(k2 * 512 + j) * 8 + g * 2 + 1] =
            (_Float16)W_hh[(size_t)(g * 512 + j) * 512 + 2 * k2 + 1];
        if (k2 < 128) {
          Wip[(size_t)(k2 * 512 + j) * 8 + g * 2 + 0] =
              (_Float16)W_ih[(size_t)(g * 512 + j) * 256 + 2 * k2 + 0];
          Wip[(size_t)(k2 * 512 + j) * 8 + g * 2 + 1] =
              (_Float16)W_ih[(size_t)(g * 512 + j) * 256 + 2 * k2 + 1];
        }
      }
    } else if (idx < NW + 2048) {
      int e = idx - NW;
      int j = e >> 2, g = e & 3;
      bsum[e] = b_ih[g * 512 + j] + b_hh[g * 512 + j];
    } else if (idx < NW + 2048 + 32768) {
      hstate[idx - (NW + 2048)] = (_Float16)0.0f;
    } else {
      cstate[idx - (NW + 2048 + 32768)] = 0.0f;
    }
  }
}

// ---------------------------------------------------------------------------
// Q: x_gates for 8 tokens per block.  Block = 512 threads, thread j owns
// hidden unit j (4 gates).  emb rows staged to LDS as f16 pairs.
// xg[tau*2048 + j*4 + g], tau = b*Tc + tl  (chunk-local step tl, t = t0+tl)
// ---------------------------------------------------------------------------
__global__ __launch_bounds__(512, 1) void xg_kernel(
    const int* __restrict__ seq, const float* __restrict__ emb,
    const _Float16* __restrict__ Wip, const float* __restrict__ bsum,
    _Float16* __restrict__ xg, int t0, int Tc) {
  __shared__ int toks[8];
  __shared__ __align__(16) _Float16 el[128 * 16];  // [k2][tok][2]
  const int tid = threadIdx.x;
  const int tau0 = blockIdx.x * 8;

  if (tid < 8) {
    int tau = tau0 + tid;
    int b = tau / Tc, tl = tau - b * Tc;
    toks[tid] = seq[b * 512 + t0 + tl];
  }
  __syncthreads();
  for (int e = tid; e < 2048; e += 512) {
    int i = e >> 8, k = e & 255;
    el[((k >> 1) * 8 + i) * 2 + (k & 1)] = (_Float16)emb[(size_t)toks[i] * 256 + k];
  }
  __syncthreads();

  const int j = tid;
  float4 bs = *(const float4*)&bsum[j * 4];
  float acc[8][4];
#pragma unroll
  for (int i = 0; i < 8; ++i) {
    acc[i][0] = bs.x; acc[i][1] = bs.y; acc[i][2] = bs.z; acc[i][3] = bs.w;
  }
  const _Float16* wp = Wip + (size_t)j * 8;
#pragma unroll 2
  for (int k2 = 0; k2 < 128; ++k2) {
    int4 w = *(const int4*)(wp + (size_t)k2 * 4096);
    int4 e0 = *(const int4*)(el + k2 * 16);
    int4 e1 = *(const int4*)(el + k2 * 16 + 8);
    acc[0][0] = dot2h(w.x, e0.x, acc[0][0]); acc[0][1] = dot2h(w.y, e0.x, acc[0][1]);
    acc[0][2] = dot2h(w.z, e0.x, acc[0][2]); acc[0][3] = dot2h(w.w, e0.x, acc[0][3]);
    acc[1][0] = dot2h(w.x, e0.y, acc[1][0]); acc[1][1] = dot2h(w.y, e0.y, acc[1][1]);
    acc[1][2] = dot2h(w.z, e0.y, acc[1][2]); acc[1][3] = dot2h(w.w, e0.y, acc[1][3]);
    acc[2][0] = dot2h(w.x, e0.z, acc[2][0]); acc[2][1] = dot2h(w.y, e0.z, acc[2][1]);
    acc[2][2] = dot2h(w.z, e0.z, acc[2][2]); acc[2][3] = dot2h(w.w, e0.z, acc[2][3]);
    acc[3][0] = dot2h(w.x, e0.w, acc[3][0]); acc[3][1] = dot2h(w.y, e0.w, acc[3][1]);
    acc[3][2] = dot2h(w.z, e0.w, acc[3][2]); acc[3][3] = dot2h(w.w, e0.w, acc[3][3]);
    acc[4][0] = dot2h(w.x, e1.x, acc[4][0]); acc[4][1] = dot2h(w.y, e1.x, acc[4][1]);
    acc[4][2] = dot2h(w.z, e1.x, acc[4][2]); acc[4][3] = dot2h(w.w, e1.x, acc[4][3]);
    acc[5][0] = dot2h(w.x, e1.y, acc[5][0]); acc[5][1] = dot2h(w.y, e1.y, acc[5][1]);
    acc[5][2] = dot2h(w.z, e1.y, acc[5][2]); acc[5][3] = dot2h(w.w, e1.y, acc[5][3]);
    acc[6][0] = dot2h(w.x, e1.z, acc[6][0]); acc[6][1] = dot2h(w.y, e1.z, acc[6][1]);
    acc[6][2] = dot2h(w.z, e1.z, acc[6][2]); acc[6][3] = dot2h(w.w, e1.z, acc[6][3]);
    acc[7][0] = dot2h(w.x, e1.w, acc[7][0]); acc[7][1] = dot2h(w.y, e1.w, acc[7][1]);
    acc[7][2] = dot2h(w.z, e1.w, acc[7][2]); acc[7][3] = dot2h(w.w, e1.w, acc[7][3]);
  }
#pragma unroll
  for (int i = 0; i < 8; ++i) {
    short4_t sv;
    sv[0] = __builtin_bit_cast(short, (_Float16)acc[i][0]);
    sv[1] = __builtin_bit_cast(short, (_Float16)acc[i][1]);
    sv[2] = __builtin_bit_cast(short, (_Float16)acc[i][2]);
    sv[3] = __builtin_bit_cast(short, (_Float16)acc[i][3]);
    *(short4_t*)(xg + ((size_t)(tau0 + i) * 512 + j) * 4) = sv;
  }
}

// ---------------------------------------------------------------------------
// R: recurrence.  grid = 64 blocks (batch), 1024 threads.
// tid<512: unit j, K in [0,256); tid>=512: same unit, K in [256,512).
// Partial sums combined through LDS ps[4][1024]; h kept as f16 in LDS.
// ---------------------------------------------------------------------------
__global__ __launch_bounds__(1024, 1) void rec_kernel(
    const _Float16* __restrict__ xg, const _Float16* __restrict__ Wp,
    _Float16* __restrict__ hstate, float* __restrict__ cstate,
    float* __restrict__ out, int t0, int Tc) {
  __shared__ __align__(16) _Float16 hl[512];
  __shared__ float ps[4][1024];
  const int b = blockIdx.x;
  const int tid = threadIdx.x;
  const int j = tid & 511;
  const int khalf = tid >> 9;

  float c = 0.0f;
  if (tid < 512) {
    hl[j] = hstate[b * 512 + j];
    c = cstate[b * 512 + j];
  }
  __syncthreads();

  const _Float16* wp = Wp + (size_t)j * 8 + (size_t)khalf * 32 * 16384;
  const _Float16* hlp = hl + khalf * 256;

  for (int tl = 0; tl < Tc; ++tl) {
    float x0 = 0.f, x1 = 0.f, x2 = 0.f, x3 = 0.f;
    if (tid < 512) {
      short4_t xs = *(const short4_t*)(xg + ((size_t)(b * Tc + tl) * 512 + j) * 4);
      x0 = (float)__builtin_bit_cast(_Float16, (short)xs[0]);
      x1 = (float)__builtin_bit_cast(_Float16, (short)xs[1]);
      x2 = (float)__builtin_bit_cast(_Float16, (short)xs[2]);
      x3 = (float)__builtin_bit_cast(_Float16, (short)xs[3]);
    }
    float A0 = 0.f, A1 = 0.f, A2 = 0.f, A3 = 0.f;
#pragma unroll 2
    for (int it = 0; it < 32; ++it) {
      int4 hq = *(const int4*)(hlp + it * 8);
      const _Float16* w = wp + (size_t)it * 16384;
      int4 w0 = *(const int4*)(w);
      int4 w1 = *(const int4*)(w + 4096);
      int4 w2 = *(const int4*)(w + 8192);
      int4 w3 = *(const int4*)(w + 12288);
      A0 = dot2h(w0.x, hq.x, A0); A1 = dot2h(w0.y, hq.x, A1);
      A2 = dot2h(w0.z, hq.x, A2); A3 = dot2h(w0.w, hq.x, A3);
      A0 = dot2h(w1.x, hq.y, A0); A1 = dot2h(w1.y, hq.y, A1);
      A2 = dot2h(w1.z, hq.y, A2); A3 = dot2h(w1.w, hq.y, A3);
      A0 = dot2h(w2.x, hq.z, A0); A1 = dot2h(w2.y, hq.z, A1);
      A2 = dot2h(w2.z, hq.z, A2); A3 = dot2h(w2.w, hq.z, A3);
      A0 = dot2h(w3.x, hq.w, A0); A1 = dot2h(w3.y, hq.w, A1);
      A2 = dot2h(w3.z, hq.w, A2); A3 = dot2h(w3.w, hq.w, A3);
    }
    ps[0][tid] = A0; ps[1][tid] = A1; ps[2][tid] = A2; ps[3][tid] = A3;
    __syncthreads();
    if (tid < 512) {
      float g0 = x0 + ps[0][j] + ps[0][j + 512];
      float g1 = x1 + ps[1][j] + ps[1][j + 512];
      float g2 = x2 + ps[2][j] + ps[2][j + 512];
      float g3 = x3 + ps[3][j] + ps[3][j + 512];
      float ig = sigm(g0), fg = sigm(g1), gg = tanh_(g2), og = sigm(g3);
      c = fg * c + ig * gg;
      float hn = og * tanh_(c);
      hl[j] = (_Float16)hn;
      if (t0 + tl == 511) {
        out[b * 512 + j] = hn;
        out[32768 + b * 512 + j] = c;
      }
    }
    __syncthreads();
  }
  if (tid < 512) {
    hstate[b * 512 + j] = hl[j];
    cstate[b * 512 + j] = c;
  }
}

// ---------------------------------------------------------------------------
// Fallback: all-f32 straight from inputs (only if ws_size is tiny).
// ---------------------------------------------------------------------------
__global__ __launch_bounds__(512, 1) void naive_kernel(
    const int* __restrict__ seq, const float* __restrict__ emb,
    const float* __restrict__ W_ih, const float* __restrict__ W_hh,
    const float* __restrict__ b_ih, const float* __restrict__ b_hh,
    float* __restrict__ out) {
  __shared__ float hl[512];
  const int b = blockIdx.x, j = threadIdx.x;
  hl[j] = 0.f;
  float c = 0.f;
  __syncthreads();
  for (int t = 0; t < 512; ++t) {
    int tok = seq[b * 512 + t];
    float A[4];
#pragma unroll
    for (int g = 0; g < 4; ++g) A[g] = b_ih[g * 512 + j] + b_hh[g * 512 + j];
    for (int k = 0; k < 256; ++k) {
      float e = emb[(size_t)tok * 256 + k];
#pragma unroll
      for (int g = 0; g < 4; ++g) A[g] += e * W_ih[(size_t)(g * 512 + j) * 256 + k];
    }
    for (int k = 0; k < 512; ++k) {
      float h = hl[k];
#pragma unroll
      for (int g = 0; g < 4; ++g) A[g] += h * W_hh[(size_t)(g * 512 + j) * 512 + k];
    }
    __syncthreads();
    float ig = sigm(A[0]), fg = sigm(A[1]), gg = tanh_(A[2]), og = sigm(A[3]);
    c = fg * c + ig * gg;
    float hn = og * tanh_(c);
    hl[j] = hn;
    __syncthreads();
    if (t == 511) {
      out[b * 512 + j] = hn;
      out[32768 + b * 512 + j] = c;
    }
  }
}

// ---------------------------------------------------------------------------
extern "C" void kernel_launch(void* const* d_in, const int* in_sizes, int n_in,
                              void* d_out, int out_size, void* d_ws, size_t ws_size,
                              hipStream_t stream) {
  const int* seq = (const int*)d_in[0];
  const float* emb = (const float*)d_in[1];
  const float* W_ih = (const float*)d_in[2];
  const float* W_hh = (const float*)d_in[3];
  const float* b_ih = (const float*)d_in[4];
  const float* b_hh = (const float*)d_in[5];
  float* out = (float*)d_out;

  // workspace layout
  char* w = (char*)d_ws;
  _Float16* Wp = (_Float16*)(w + 0);            // 2,097,152 B
  _Float16* Wip = (_Float16*)(w + 2097152);     // 1,048,576 B
  float* bsum = (float*)(w + 3145728);          //     8,192 B
  _Float16* hstate = (_Float16*)(w + 3153920);  //    65,536 B
  float* cstate = (float*)(w + 3219456);        //   131,072 B
  _Float16* xgbuf = (_Float16*)(w + 3350528);   // Tc*262,144 B
  const size_t base = 3350528;

  int Tc = 0;
  const int cands[7] = {512, 256, 128, 64, 32, 16, 8};
  for (int ci = 0; ci < 7; ++ci) {
    if (base + (size_t)cands[ci] * 262144 <= ws_size) { Tc = cands[ci]; break; }
  }

  if (Tc == 0) {
    naive_kernel<<<64, 512, 0, stream>>>(seq, emb, W_ih, W_hh, b_ih, b_hh, out);
    return;
  }

  prep_kernel<<<512, 256, 0, stream>>>(W_hh, W_ih, b_ih, b_hh, Wp, Wip, bsum,
                                       hstate, cstate);
  for (int t0 = 0; t0 < 512; t0 += Tc) {
    xg_kernel<<<8 * Tc, 512, 0, stream>>>(seq, emb, Wip, bsum, xgbuf, t0, Tc);
    rec_kernel<<<64, 1024, 0, stream>>>(xgbuf, Wp, hstate, cstate, out, t0, Tc);
  }
}